// Round 1
// baseline (7596.117 us; speedup 1.0000x reference)
//
#include <hip/hip_runtime.h>
#include <hip/hip_bf16.h>
#include <math.h>

#define EPS 1e-5f

// ---------------- LayerNorm: one block (256 thr) per row of 512 ----------------
__global__ __launch_bounds__(256) void ln_kernel(const float* __restrict__ in,
                                                 const float* __restrict__ w,
                                                 const float* __restrict__ bb,
                                                 float* __restrict__ out) {
    int row = blockIdx.x;
    const float* x = in + (size_t)row * 512;
    float* o = out + (size_t)row * 512;
    int t = threadIdx.x;
    float v0 = x[t], v1 = x[t + 256];
    float s = v0 + v1;
    float s2 = v0 * v0 + v1 * v1;
    for (int off = 32; off > 0; off >>= 1) {
        s  += __shfl_down(s, off);
        s2 += __shfl_down(s2, off);
    }
    __shared__ float rs_[4], rs2_[4];
    __shared__ float mu_s, rstd_s;
    int wid = t >> 6;
    if ((t & 63) == 0) { rs_[wid] = s; rs2_[wid] = s2; }
    __syncthreads();
    if (t == 0) {
        float ts  = rs_[0] + rs_[1] + rs_[2] + rs_[3];
        float ts2 = rs2_[0] + rs2_[1] + rs2_[2] + rs2_[3];
        float mu  = ts * (1.f / 512.f);
        float var = ts2 * (1.f / 512.f) - mu * mu;
        mu_s = mu;
        rstd_s = rsqrtf(var + EPS);
    }
    __syncthreads();
    float mu = mu_s, rstd = rstd_s;
    o[t]       = (v0 - mu) * rstd * w[t]       + bb[t];
    o[t + 256] = (v1 - mu) * rstd * w[t + 256] + bb[t + 256];
}

// ---------------- fp32 tiled GEMM: C[M,N] = A[M,K] @ B[K,N] (+ res) ----------------
// 64x64 tile, 16x16 threads, 4x4 outputs/thread, K-tile 16.
template <int EPI>  // 0: C = A@B ; 1: C = res + A@B
__global__ __launch_bounds__(256) void gemm_kernel(const float* __restrict__ A,
                                                   const float* __restrict__ B,
                                                   const float* __restrict__ res,
                                                   float* __restrict__ C,
                                                   int M, int N, int K) {
    __shared__ float As[64][17];
    __shared__ float Bs[16][65];
    int tx = threadIdx.x, ty = threadIdx.y;
    int tid = ty * 16 + tx;
    int n0 = blockIdx.x * 64;
    int m0 = blockIdx.y * 64;
    float acc[4][4] = {};
    for (int k0 = 0; k0 < K; k0 += 16) {
        {
            int r = (tid * 4) >> 4;
            int c = (tid * 4) & 15;
            const float4 av = *(const float4*)(&A[(size_t)(m0 + r) * K + k0 + c]);
            As[r][c + 0] = av.x; As[r][c + 1] = av.y; As[r][c + 2] = av.z; As[r][c + 3] = av.w;
        }
        {
            int r = (tid * 4) >> 6;
            int c = (tid * 4) & 63;
            const float4 bv = *(const float4*)(&B[(size_t)(k0 + r) * N + n0 + c]);
            Bs[r][c + 0] = bv.x; Bs[r][c + 1] = bv.y; Bs[r][c + 2] = bv.z; Bs[r][c + 3] = bv.w;
        }
        __syncthreads();
#pragma unroll
        for (int kk = 0; kk < 16; kk++) {
            float a[4], b[4];
#pragma unroll
            for (int i = 0; i < 4; i++) a[i] = As[ty * 4 + i][kk];
#pragma unroll
            for (int j = 0; j < 4; j++) b[j] = Bs[kk][tx * 4 + j];
#pragma unroll
            for (int i = 0; i < 4; i++)
#pragma unroll
                for (int j = 0; j < 4; j++) acc[i][j] = fmaf(a[i], b[j], acc[i][j]);
        }
        __syncthreads();
    }
#pragma unroll
    for (int i = 0; i < 4; i++) {
        int m = m0 + ty * 4 + i;
#pragma unroll
        for (int j = 0; j < 4; j++) {
            int n = n0 + tx * 4 + j;
            float vres = (EPI == 1) ? res[(size_t)m * N + n] : 0.f;
            C[(size_t)m * N + n] = vres + acc[i][j];
        }
    }
}

// ---------------- attention: one block per (b, h, q-row); full softmax in LDS ----------------
__global__ __launch_bounds__(256) void attn_kernel(const float* __restrict__ q,
                                                   const float* __restrict__ kmat,
                                                   const float* __restrict__ vmat,
                                                   float* __restrict__ out) {
    const int L = 2048, HD = 512, DH = 64;
    int qi = blockIdx.x, h = blockIdx.y, b = blockIdx.z;
    __shared__ float s[2048];
    __shared__ float qs[64];
    __shared__ float red[4];
    __shared__ float red2[4][64];
    int t = threadIdx.x;
    size_t base = ((size_t)b * L) * HD + (size_t)h * DH;
    if (t < DH) qs[t] = q[base + (size_t)qi * HD + t] * 0.125f;  // scale = Dh^-0.5
    __syncthreads();
    // phase 1: scores
    float lmax = -1e30f;
    for (int kk = t; kk < L; kk += 256) {
        const float* krow = kmat + base + (size_t)kk * HD;
        float acc = 0.f;
#pragma unroll
        for (int d = 0; d < DH; d++) acc = fmaf(qs[d], krow[d], acc);
        s[kk] = acc;
        lmax = fmaxf(lmax, acc);
    }
    for (int off = 32; off > 0; off >>= 1) lmax = fmaxf(lmax, __shfl_down(lmax, off));
    if ((t & 63) == 0) red[t >> 6] = lmax;
    __syncthreads();
    float mx = fmaxf(fmaxf(red[0], red[1]), fmaxf(red[2], red[3]));
    // phase 2: exp + sum
    float lsum = 0.f;
    for (int kk = t; kk < L; kk += 256) {
        float e = expf(s[kk] - mx);
        s[kk] = e;
        lsum += e;
    }
    for (int off = 32; off > 0; off >>= 1) lsum += __shfl_down(lsum, off);
    __syncthreads();  // all reads of red (mx) and writes of s done
    if ((t & 63) == 0) red[t >> 6] = lsum;
    __syncthreads();
    float ssum = red[0] + red[1] + red[2] + red[3];
    // phase 3: P @ V  (wave g handles keys g, g+4, ...; lane d accumulates dim d)
    int d = t & 63, g = t >> 6;
    float acc = 0.f;
    for (int kk = g; kk < L; kk += 4)
        acc = fmaf(s[kk], vmat[base + (size_t)kk * HD + d], acc);
    red2[g][d] = acc;
    __syncthreads();
    if (g == 0) {
        float r = (red2[0][d] + red2[1][d] + red2[2][d] + red2[3][d]) / ssum;
        out[base + (size_t)qi * HD + d] = r;
    }
}

// ---------------- silu(g) * u ----------------
__global__ __launch_bounds__(256) void silumul_kernel(const float* __restrict__ g,
                                                      const float* __restrict__ u,
                                                      float* __restrict__ o, int n) {
    int i = blockIdx.x * 256 + threadIdx.x;
    if (i < n) {
        float x = g[i];
        float sig = 1.f / (1.f + expf(-x));
        o[i] = x * sig * u[i];
    }
}

extern "C" void kernel_launch(void* const* d_in, const int* in_sizes, int n_in,
                              void* d_out, int out_size, void* d_ws, size_t ws_size,
                              hipStream_t stream) {
    const float* x      = (const float*)d_in[0];
    const float* ln1_w  = (const float*)d_in[1];
    const float* ln1_b  = (const float*)d_in[2];
    const float* ln2_w  = (const float*)d_in[3];
    const float* ln2_b  = (const float*)d_in[4];
    const float* wq     = (const float*)d_in[5];
    const float* wk     = (const float*)d_in[6];
    const float* wv     = (const float*)d_in[7];
    const float* wo     = (const float*)d_in[8];
    const float* w_gate = (const float*)d_in[9];
    const float* w_up   = (const float*)d_in[10];
    const float* w_down = (const float*)d_in[11];
    float* out = (float*)d_out;

    const int M = 4 * 2048;  // 8192 rows
    char* ws = (char*)d_ws;
    // layout (peak 96 MB): [0,16M) h1/attnout, [16M,32M) q/h2, [32M,48M) k,
    // [48M,64M) v, [32M,64M) g (after attn, k/v dead), [64M,96M) u
    float* h1      = (float*)(ws);
    float* q       = (float*)(ws + (size_t)(16 << 20));
    float* kbuf    = (float*)(ws + (size_t)(32 << 20));
    float* vbuf    = (float*)(ws + (size_t)(48 << 20));
    float* g       = (float*)(ws + (size_t)(32 << 20));
    float* u       = (float*)(ws + (size_t)(64 << 20));
    float* attnout = h1;
    float* h2      = q;

    dim3 gthr(16, 16);
    dim3 gblk(512 / 64, M / 64);    // N=512
    dim3 gblk2(1024 / 64, M / 64);  // N=1024

    ln_kernel<<<M, 256, 0, stream>>>(x, ln1_w, ln1_b, h1);
    gemm_kernel<0><<<gblk, gthr, 0, stream>>>(h1, wq, nullptr, q, M, 512, 512);
    gemm_kernel<0><<<gblk, gthr, 0, stream>>>(h1, wk, nullptr, kbuf, M, 512, 512);
    gemm_kernel<0><<<gblk, gthr, 0, stream>>>(h1, wv, nullptr, vbuf, M, 512, 512);
    attn_kernel<<<dim3(2048, 8, 4), 256, 0, stream>>>(q, kbuf, vbuf, attnout);
    gemm_kernel<1><<<gblk, gthr, 0, stream>>>(attnout, wo, x, out, M, 512, 512);
    ln_kernel<<<M, 256, 0, stream>>>(out, ln2_w, ln2_b, h2);
    gemm_kernel<0><<<gblk2, gthr, 0, stream>>>(h2, w_gate, nullptr, g, M, 1024, 512);
    gemm_kernel<0><<<gblk2, gthr, 0, stream>>>(h2, w_up, nullptr, u, M, 1024, 512);
    silumul_kernel<<<(M * 1024 + 255) / 256, 256, 0, stream>>>(g, u, g, M * 1024);
    gemm_kernel<1><<<gblk, gthr, 0, stream>>>(g, w_down, out, out, M, 512, 1024);
}

// Round 2
// 1042.736 us; speedup vs baseline: 7.2848x; 7.2848x over previous
//
#include <hip/hip_runtime.h>
#include <hip/hip_bf16.h>
#include <math.h>

#define EPS 1e-5f

typedef __attribute__((ext_vector_type(8))) short bf16x8;
typedef __attribute__((ext_vector_type(4))) float f32x4;

__device__ inline short f2bf(float x) {
    union { float f; unsigned u; } un; un.f = x;
    unsigned r = un.u + 0x7FFF + ((un.u >> 16) & 1);  // RNE
    return (short)(r >> 16);
}

// ---------------- LayerNorm: one block (256 thr) per row of 512 ----------------
__global__ __launch_bounds__(256) void ln_kernel(const float* __restrict__ in,
                                                 const float* __restrict__ w,
                                                 const float* __restrict__ bb,
                                                 float* __restrict__ out) {
    int row = blockIdx.x;
    const float* x = in + (size_t)row * 512;
    float* o = out + (size_t)row * 512;
    int t = threadIdx.x;
    float v0 = x[t], v1 = x[t + 256];
    float s = v0 + v1;
    float s2 = v0 * v0 + v1 * v1;
    for (int off = 32; off > 0; off >>= 1) {
        s  += __shfl_down(s, off);
        s2 += __shfl_down(s2, off);
    }
    __shared__ float rs_[4], rs2_[4];
    __shared__ float mu_s, rstd_s;
    int wid = t >> 6;
    if ((t & 63) == 0) { rs_[wid] = s; rs2_[wid] = s2; }
    __syncthreads();
    if (t == 0) {
        float ts  = rs_[0] + rs_[1] + rs_[2] + rs_[3];
        float ts2 = rs2_[0] + rs2_[1] + rs2_[2] + rs2_[3];
        float mu  = ts * (1.f / 512.f);
        float var = ts2 * (1.f / 512.f) - mu * mu;
        mu_s = mu;
        rstd_s = rsqrtf(var + EPS);
    }
    __syncthreads();
    float mu = mu_s, rstd = rstd_s;
    o[t]       = (v0 - mu) * rstd * w[t]       + bb[t];
    o[t + 256] = (v1 - mu) * rstd * w[t + 256] + bb[t + 256];
}

// ---------------- fp32 tiled GEMM: C[M,N] = A[M,K] @ B[K,N] (+ res) ----------------
template <int EPI>  // 0: C = A@B ; 1: C = res + A@B
__global__ __launch_bounds__(256) void gemm_kernel(const float* __restrict__ A,
                                                   const float* __restrict__ B,
                                                   const float* __restrict__ res,
                                                   float* __restrict__ C,
                                                   int M, int N, int K) {
    __shared__ float As[64][17];
    __shared__ float Bs[16][65];
    int tx = threadIdx.x, ty = threadIdx.y;
    int tid = ty * 16 + tx;
    int n0 = blockIdx.x * 64;
    int m0 = blockIdx.y * 64;
    float acc[4][4] = {};
    for (int k0 = 0; k0 < K; k0 += 16) {
        {
            int r = (tid * 4) >> 4;
            int c = (tid * 4) & 15;
            const float4 av = *(const float4*)(&A[(size_t)(m0 + r) * K + k0 + c]);
            As[r][c + 0] = av.x; As[r][c + 1] = av.y; As[r][c + 2] = av.z; As[r][c + 3] = av.w;
        }
        {
            int r = (tid * 4) >> 6;
            int c = (tid * 4) & 63;
            const float4 bv = *(const float4*)(&B[(size_t)(k0 + r) * N + n0 + c]);
            Bs[r][c + 0] = bv.x; Bs[r][c + 1] = bv.y; Bs[r][c + 2] = bv.z; Bs[r][c + 3] = bv.w;
        }
        __syncthreads();
#pragma unroll
        for (int kk = 0; kk < 16; kk++) {
            float a[4], b[4];
#pragma unroll
            for (int i = 0; i < 4; i++) a[i] = As[ty * 4 + i][kk];
#pragma unroll
            for (int j = 0; j < 4; j++) b[j] = Bs[kk][tx * 4 + j];
#pragma unroll
            for (int i = 0; i < 4; i++)
#pragma unroll
                for (int j = 0; j < 4; j++) acc[i][j] = fmaf(a[i], b[j], acc[i][j]);
        }
        __syncthreads();
    }
#pragma unroll
    for (int i = 0; i < 4; i++) {
        int m = m0 + ty * 4 + i;
#pragma unroll
        for (int j = 0; j < 4; j++) {
            int n = n0 + tx * 4 + j;
            float vres = (EPI == 1) ? res[(size_t)m * N + n] : 0.f;
            C[(size_t)m * N + n] = vres + acc[i][j];
        }
    }
}

// ---------------- pack q/k: fp32 [b,l,h*64+d] -> bf16 [b,h,l,d] ----------------
__global__ __launch_bounds__(256) void pack_qk_kernel(const float* __restrict__ src,
                                                      short* __restrict__ dst) {
    size_t i = ((size_t)blockIdx.x * 256 + threadIdx.x) * 4;  // idx in [b][h][l][d]
    int d = (int)(i & 63);
    int l = (int)((i >> 6) & 2047);
    int bh = (int)(i >> 17);
    int h = bh & 7, b = bh >> 3;
    const float4 vv = *(const float4*)&src[((size_t)b * 2048 + l) * 512 + h * 64 + d];
    short4 o;
    o.x = f2bf(vv.x); o.y = f2bf(vv.y); o.z = f2bf(vv.z); o.w = f2bf(vv.w);
    *(short4*)&dst[i] = o;
}

// ---------------- pack v transposed: fp32 [b,l,h*64+d] -> bf16 [b,h,d,l] ----------------
__global__ __launch_bounds__(256) void pack_vt_kernel(const float* __restrict__ v,
                                                      short* __restrict__ vt) {
    __shared__ short tile[64][68];
    int l0 = blockIdx.x * 64;
    int bh = blockIdx.y;
    int h = bh & 7, b = bh >> 3;
    int tid = threadIdx.x;
#pragma unroll
    for (int p = 0; p < 4; p++) {
        int r = p * 16 + (tid >> 4);
        int c4 = (tid & 15) * 4;
        const float4 vv = *(const float4*)&v[((size_t)(b * 2048 + l0 + r)) * 512 + h * 64 + c4];
        tile[r][c4 + 0] = f2bf(vv.x); tile[r][c4 + 1] = f2bf(vv.y);
        tile[r][c4 + 2] = f2bf(vv.z); tile[r][c4 + 3] = f2bf(vv.w);
    }
    __syncthreads();
#pragma unroll
    for (int p = 0; p < 4; p++) {
        int d = p * 16 + (tid >> 4);
        int c4 = (tid & 15) * 4;
        short4 o;
        o.x = tile[c4 + 0][d]; o.y = tile[c4 + 1][d];
        o.z = tile[c4 + 2][d]; o.w = tile[c4 + 3][d];
        *(short4*)&vt[(size_t)bh * (64 * 2048) + (size_t)d * 2048 + l0 + c4] = o;
    }
}

// ---------------- MFMA flash attention ----------------
// grid (32 q-tiles, 32 bh), 256 thr (4 waves). Wave w owns q-rows 16w..16w+15 of a
// 64-row Q tile. K-tile = 64 keys. mfma_f32_16x16x32_bf16 for QK^T and PV.
__global__ __launch_bounds__(256) void attn_mfma_kernel(const short* __restrict__ qb,
                                                        const short* __restrict__ kb,
                                                        const short* __restrict__ vt,
                                                        float* __restrict__ out) {
    __shared__ __align__(16) short Qs[64][72];
    __shared__ __align__(16) short Ks[64][72];
    __shared__ __align__(16) short Vts[64][72];
    __shared__ __align__(16) short Ps[64][72];
    int q0 = blockIdx.x * 64;
    int bh = blockIdx.y;
    int h = bh & 7, b = bh >> 3;
    int tid = threadIdx.x;
    int lane = tid & 63, w = tid >> 6;
    int g = lane >> 4, r16 = lane & 15;
    const size_t hb = (size_t)bh * (2048 * 64);

    // stage Q tile (64x64 bf16)
#pragma unroll
    for (int p = 0; p < 4; p++) {
        int row = p * 16 + (tid >> 4);
        int c4 = (tid & 15) * 4;
        *(short4*)&Qs[row][c4] = *(const short4*)&qb[hb + (size_t)(q0 + row) * 64 + c4];
    }

    float m_[4], l_[4];
    f32x4 o_[4];
#pragma unroll
    for (int j = 0; j < 4; j++) { m_[j] = -1e30f; l_[j] = 0.f; }
#pragma unroll
    for (int c = 0; c < 4; c++) o_[c] = (f32x4)(0.f);

    for (int kt = 0; kt < 32; kt++) {
        int k0 = kt * 64;
        __syncthreads();  // prior reads of Ks/Vts done (also covers Q staging on iter 0)
#pragma unroll
        for (int p = 0; p < 4; p++) {
            int row = p * 16 + (tid >> 4);
            int c4 = (tid & 15) * 4;
            *(short4*)&Ks[row][c4]  = *(const short4*)&kb[hb + (size_t)(k0 + row) * 64 + c4];
            *(short4*)&Vts[row][c4] = *(const short4*)&vt[hb + (size_t)row * 2048 + k0 + c4];
        }
        __syncthreads();

        // ---- QK^T: S[16 x 64] per wave ----
        bf16x8 aq0 = *(bf16x8*)&Qs[16 * w + r16][8 * g];
        bf16x8 aq1 = *(bf16x8*)&Qs[16 * w + r16][32 + 8 * g];
        f32x4 s[4];
#pragma unroll
        for (int c = 0; c < 4; c++) {
            bf16x8 bk0 = *(bf16x8*)&Ks[16 * c + r16][8 * g];
            bf16x8 bk1 = *(bf16x8*)&Ks[16 * c + r16][32 + 8 * g];
            f32x4 acc = (f32x4)(0.f);
            acc = __builtin_amdgcn_mfma_f32_16x16x32_bf16(aq0, bk0, acc, 0, 0, 0);
            acc = __builtin_amdgcn_mfma_f32_16x16x32_bf16(aq1, bk1, acc, 0, 0, 0);
            s[c] = acc;
        }

        // ---- online softmax (rows = 4g+j, cols across 16 lanes of the group) ----
        float rm[4];
#pragma unroll
        for (int j = 0; j < 4; j++)
            rm[j] = fmaxf(fmaxf(s[0][j], s[1][j]), fmaxf(s[2][j], s[3][j])) * 0.125f;
#pragma unroll
        for (int off = 1; off < 16; off <<= 1)
#pragma unroll
            for (int j = 0; j < 4; j++) rm[j] = fmaxf(rm[j], __shfl_xor(rm[j], off));
        float alpha[4];
#pragma unroll
        for (int j = 0; j < 4; j++) {
            float mn = fmaxf(m_[j], rm[j]);
            alpha[j] = __expf(m_[j] - mn);
            m_[j] = mn;
        }
        float rs[4] = {0.f, 0.f, 0.f, 0.f};
        short pb[4][4];
#pragma unroll
        for (int c = 0; c < 4; c++)
#pragma unroll
            for (int j = 0; j < 4; j++) {
                float p = __expf(s[c][j] * 0.125f - m_[j]);
                rs[j] += p;
                pb[c][j] = f2bf(p);
            }
#pragma unroll
        for (int off = 1; off < 16; off <<= 1)
#pragma unroll
            for (int j = 0; j < 4; j++) rs[j] += __shfl_xor(rs[j], off);
#pragma unroll
        for (int j = 0; j < 4; j++) l_[j] = l_[j] * alpha[j] + rs[j];

        // P -> LDS (per-wave 16-row slice; within-wave dependency only)
#pragma unroll
        for (int c = 0; c < 4; c++)
#pragma unroll
            for (int j = 0; j < 4; j++)
                Ps[16 * w + 4 * g + j][16 * c + r16] = pb[c][j];
        // rescale O
#pragma unroll
        for (int c = 0; c < 4; c++)
#pragma unroll
            for (int j = 0; j < 4; j++) o_[c][j] *= alpha[j];

        // ---- PV: O[16 x 64] += P[16 x 64keys] @ V[64keys x 64] ----
        bf16x8 ap0 = *(bf16x8*)&Ps[16 * w + r16][8 * g];
        bf16x8 ap1 = *(bf16x8*)&Ps[16 * w + r16][32 + 8 * g];
#pragma unroll
        for (int c = 0; c < 4; c++) {
            bf16x8 bv0 = *(bf16x8*)&Vts[16 * c + r16][8 * g];
            bf16x8 bv1 = *(bf16x8*)&Vts[16 * c + r16][32 + 8 * g];
            o_[c] = __builtin_amdgcn_mfma_f32_16x16x32_bf16(ap0, bv0, o_[c], 0, 0, 0);
            o_[c] = __builtin_amdgcn_mfma_f32_16x16x32_bf16(ap1, bv1, o_[c], 0, 0, 0);
        }
    }

    // epilogue: normalize, store fp32 to [b, l, h*64+d]
#pragma unroll
    for (int c = 0; c < 4; c++)
#pragma unroll
        for (int j = 0; j < 4; j++) {
            int qr = q0 + 16 * w + 4 * g + j;
            int d = 16 * c + r16;
            out[((size_t)b * 2048 + qr) * 512 + h * 64 + d] = o_[c][j] / l_[j];
        }
}

// ---------------- silu(g) * u ----------------
__global__ __launch_bounds__(256) void silumul_kernel(const float* __restrict__ g,
                                                      const float* __restrict__ u,
                                                      float* __restrict__ o, int n) {
    int i = blockIdx.x * 256 + threadIdx.x;
    if (i < n) {
        float x = g[i];
        float sig = 1.f / (1.f + expf(-x));
        o[i] = x * sig * u[i];
    }
}

extern "C" void kernel_launch(void* const* d_in, const int* in_sizes, int n_in,
                              void* d_out, int out_size, void* d_ws, size_t ws_size,
                              hipStream_t stream) {
    const float* x      = (const float*)d_in[0];
    const float* ln1_w  = (const float*)d_in[1];
    const float* ln1_b  = (const float*)d_in[2];
    const float* ln2_w  = (const float*)d_in[3];
    const float* ln2_b  = (const float*)d_in[4];
    const float* wq     = (const float*)d_in[5];
    const float* wk     = (const float*)d_in[6];
    const float* wv     = (const float*)d_in[7];
    const float* wo     = (const float*)d_in[8];
    const float* w_gate = (const float*)d_in[9];
    const float* w_up   = (const float*)d_in[10];
    const float* w_down = (const float*)d_in[11];
    float* out = (float*)d_out;

    const int M = 4 * 2048;  // 8192 rows
    char* ws = (char*)d_ws;
    // layout (peak 96 MB):
    //   [0,16M)  h1 / attnout
    //   [16,32M) q fp32 / h2
    //   [32,48M) k fp32        } after attn: g reuses [32,64M)
    //   [48,64M) v fp32
    //   [64,72M) qb bf16  } dead after attn; u reuses [64,96M)
    //   [72,80M) kb bf16
    //   [80,88M) vt bf16
    float* h1      = (float*)(ws);
    float* q       = (float*)(ws + (size_t)(16 << 20));
    float* kbuf    = (float*)(ws + (size_t)(32 << 20));
    float* vbuf    = (float*)(ws + (size_t)(48 << 20));
    short* qb      = (short*)(ws + (size_t)(64 << 20));
    short* kb      = (short*)(ws + (size_t)(72 << 20));
    short* vt      = (short*)(ws + (size_t)(80 << 20));
    float* g       = (float*)(ws + (size_t)(32 << 20));
    float* u       = (float*)(ws + (size_t)(64 << 20));
    float* attnout = h1;
    float* h2      = q;

    dim3 gthr(16, 16);
    dim3 gblk(512 / 64, M / 64);    // N=512
    dim3 gblk2(1024 / 64, M / 64);  // N=1024

    ln_kernel<<<M, 256, 0, stream>>>(x, ln1_w, ln1_b, h1);
    gemm_kernel<0><<<gblk, gthr, 0, stream>>>(h1, wq, nullptr, q, M, 512, 512);
    gemm_kernel<0><<<gblk, gthr, 0, stream>>>(h1, wk, nullptr, kbuf, M, 512, 512);
    gemm_kernel<0><<<gblk, gthr, 0, stream>>>(h1, wv, nullptr, vbuf, M, 512, 512);
    pack_qk_kernel<<<4096, 256, 0, stream>>>(q, qb);
    pack_qk_kernel<<<4096, 256, 0, stream>>>(kbuf, kb);
    pack_vt_kernel<<<dim3(32, 32), 256, 0, stream>>>(vbuf, vt);
    attn_mfma_kernel<<<dim3(32, 32), 256, 0, stream>>>(qb, kb, vt, attnout);
    gemm_kernel<1><<<gblk, gthr, 0, stream>>>(attnout, wo, x, out, M, 512, 512);
    ln_kernel<<<M, 256, 0, stream>>>(out, ln2_w, ln2_b, h2);
    gemm_kernel<0><<<gblk2, gthr, 0, stream>>>(h2, w_gate, nullptr, g, M, 1024, 512);
    gemm_kernel<0><<<gblk2, gthr, 0, stream>>>(h2, w_up, nullptr, u, M, 1024, 512);
    silumul_kernel<<<(M * 1024 + 255) / 256, 256, 0, stream>>>(g, u, g, M * 1024);
    gemm_kernel<1><<<gblk, gthr, 0, stream>>>(g, w_down, out, out, M, 512, 1024);
}

// Round 3
// 294.259 us; speedup vs baseline: 25.8144x; 3.5436x over previous
//
#include <hip/hip_runtime.h>
#include <hip/hip_bf16.h>
#include <math.h>

#define EPS 1e-5f

typedef __attribute__((ext_vector_type(8))) short bf16x8;
typedef __attribute__((ext_vector_type(4))) float f32x4;

__device__ __forceinline__ short f2bf(float x) {
    union { float f; unsigned u; } un; un.f = x;
    unsigned r = un.u + 0x7FFF + ((un.u >> 16) & 1);  // RNE
    return (short)(r >> 16);
}
__device__ __forceinline__ float bf2f(short s) {
    union { unsigned u; float f; } un;
    un.u = ((unsigned)(unsigned short)s) << 16;
    return un.f;
}
__device__ __forceinline__ void load_lds16(const short* g, short* l) {
    __builtin_amdgcn_global_load_lds(
        (const __attribute__((address_space(1))) unsigned int*)g,
        (__attribute__((address_space(3))) unsigned int*)l, 16, 0, 0);
}

// ---------------- LayerNorm: fp32 in -> bf16 out, one block per row ----------------
__global__ __launch_bounds__(256) void ln_kernel_b(const float* __restrict__ in,
                                                   const float* __restrict__ w,
                                                   const float* __restrict__ bb,
                                                   short* __restrict__ out) {
    int row = blockIdx.x;
    const float* x = in + (size_t)row * 512;
    short* o = out + (size_t)row * 512;
    int t = threadIdx.x;
    float v0 = x[t], v1 = x[t + 256];
    float s = v0 + v1;
    float s2 = v0 * v0 + v1 * v1;
    for (int off = 32; off > 0; off >>= 1) {
        s  += __shfl_down(s, off);
        s2 += __shfl_down(s2, off);
    }
    __shared__ float rs_[4], rs2_[4];
    __shared__ float mu_s, rstd_s;
    int wid = t >> 6;
    if ((t & 63) == 0) { rs_[wid] = s; rs2_[wid] = s2; }
    __syncthreads();
    if (t == 0) {
        float ts  = rs_[0] + rs_[1] + rs_[2] + rs_[3];
        float ts2 = rs2_[0] + rs2_[1] + rs2_[2] + rs2_[3];
        float mu  = ts * (1.f / 512.f);
        float var = ts2 * (1.f / 512.f) - mu * mu;
        mu_s = mu;
        rstd_s = rsqrtf(var + EPS);
    }
    __syncthreads();
    float mu = mu_s, rstd = rstd_s;
    o[t]       = f2bf((v0 - mu) * rstd * w[t]       + bb[t]);
    o[t + 256] = f2bf((v1 - mu) * rstd * w[t + 256] + bb[t + 256]);
}

// ---------------- weight transpose+cast: w[K][N] fp32 -> bt[N][K] bf16 (7 at once) ----------------
struct WT { const float* w; short* t; int K; int N; };
struct WT7 { WT a[7]; };
__global__ __launch_bounds__(256) void transp_w_kernel(WT7 p) {
    WT e = p.a[blockIdx.z];
    int k0 = blockIdx.x * 32, n0 = blockIdx.y * 32;
    if (k0 >= e.K || n0 >= e.N) return;
    __shared__ short t[32][33];
    int tx = threadIdx.x & 31, ty = threadIdx.x >> 5;  // 32 x 8
#pragma unroll
    for (int pp = 0; pp < 4; pp++)
        t[pp * 8 + ty][tx] = f2bf(e.w[(size_t)(k0 + pp * 8 + ty) * e.N + n0 + tx]);
    __syncthreads();
#pragma unroll
    for (int pp = 0; pp < 4; pp++)
        e.t[(size_t)(n0 + pp * 8 + ty) * e.K + k0 + tx] = t[tx][pp * 8 + ty];
}

// ---------------- bf16 MFMA GEMM: C[M,N] = A[M,K] @ Bt[N,K]^T ----------------
// 128x128 tile, BK=64, 256 thr (4 waves 2x2), mfma_f32_16x16x32_bf16, 4x4 frags/wave.
// LDS staged via global_load_lds w16, XOR-swizzled (inverse-swizzle on source).
// EPI: 0 = fp32 C = res + acc      (C row-major [M][N])
//      1 = bf16 C = acc            (row-major)
//      2 = bf16 packed [b,h,l,d]   (M=b*2048+l, N=h*64+d)
template <int EPI>
__global__ __launch_bounds__(256) void gemm_mfma(const short* __restrict__ A,
                                                 const short* __restrict__ Bt,
                                                 const float* __restrict__ res,
                                                 void* __restrict__ Cv,
                                                 int M, int N, int K) {
    __shared__ short As[128 * 64];
    __shared__ short Bs[128 * 64];
    const int tid = threadIdx.x;
    const int lane = tid & 63, w = tid >> 6;
    const int g = lane >> 4, r16 = lane & 15;
    const int wr = w >> 1, wc = w & 1;
    const int m0 = blockIdx.y * 128, n0 = blockIdx.x * 128;

    const int lr = lane >> 3;        // row within 8-row group (0..7)
    const int ck = (lane & 7) ^ lr;  // inverse-swizzled source chunk
    const int row0 = w * 32;         // this wave stages rows [row0, row0+32)

    f32x4 acc[4][4] = {};

    for (int k0 = 0; k0 < K; k0 += 64) {
        __syncthreads();  // previous tile's compute done before overwrite
#pragma unroll
        for (int p = 0; p < 4; p++) {
            int rb = row0 + p * 8;
            load_lds16(&A [(size_t)(m0 + rb + lr) * K + k0 + ck * 8], &As[rb * 64]);
            load_lds16(&Bt[(size_t)(n0 + rb + lr) * K + k0 + ck * 8], &Bs[rb * 64]);
        }
        __syncthreads();
#pragma unroll
        for (int ks = 0; ks < 2; ks++) {
            bf16x8 av[4], bv[4];
#pragma unroll
            for (int i = 0; i < 4; i++) {
                int row = wr * 64 + i * 16 + r16;
                av[i] = *(const bf16x8*)&As[row * 64 + ((ks * 4 + g) ^ (row & 7)) * 8];
            }
#pragma unroll
            for (int j = 0; j < 4; j++) {
                int row = wc * 64 + j * 16 + r16;
                bv[j] = *(const bf16x8*)&Bs[row * 64 + ((ks * 4 + g) ^ (row & 7)) * 8];
            }
#pragma unroll
            for (int i = 0; i < 4; i++)
#pragma unroll
                for (int j = 0; j < 4; j++)
                    acc[i][j] = __builtin_amdgcn_mfma_f32_16x16x32_bf16(av[i], bv[j], acc[i][j], 0, 0, 0);
        }
    }

#pragma unroll
    for (int i = 0; i < 4; i++)
#pragma unroll
        for (int j = 0; j < 4; j++)
#pragma unroll
            for (int jr = 0; jr < 4; jr++) {
                int m = m0 + wr * 64 + i * 16 + 4 * g + jr;
                int n = n0 + wc * 64 + j * 16 + r16;
                float v = acc[i][j][jr];
                if (EPI == 0) {
                    size_t idx = (size_t)m * N + n;
                    ((float*)Cv)[idx] = res[idx] + v;
                } else if (EPI == 1) {
                    ((short*)Cv)[(size_t)m * N + n] = f2bf(v);
                } else {
                    // [b,h,l,d] = [m>>11, n>>6, m&2047, n&63]
                    ((short*)Cv)[(((size_t)(m >> 11) * 8 + (n >> 6)) * 2048 + (m & 2047)) * 64 + (n & 63)] = f2bf(v);
                }
            }
}

// ---------------- bf16 transpose V: [b,h,l,d] -> [b,h,d,l] ----------------
__global__ __launch_bounds__(256) void transp_v_kernel(const short* __restrict__ vb,
                                                       short* __restrict__ vt) {
    __shared__ short tile[64][65];
    int l0 = blockIdx.x * 64;
    int bh = blockIdx.y;
    const size_t base = (size_t)bh * 2048 * 64;
    int tid = threadIdx.x;
#pragma unroll
    for (int p = 0; p < 4; p++) {
        int r = p * 16 + (tid >> 4);
        int c4 = (tid & 15) * 4;
        *(short4*)&tile[r][c4] = *(const short4*)&vb[base + (size_t)(l0 + r) * 64 + c4];
    }
    __syncthreads();
#pragma unroll
    for (int p = 0; p < 4; p++) {
        int d = p * 16 + (tid >> 4);
        int c4 = (tid & 15) * 4;
        short4 o;
        o.x = tile[c4 + 0][d]; o.y = tile[c4 + 1][d];
        o.z = tile[c4 + 2][d]; o.w = tile[c4 + 3][d];
        *(short4*)&vt[base + (size_t)d * 2048 + l0 + c4] = o;
    }
}

// ---------------- MFMA flash attention (bf16 in, bf16 out) ----------------
__global__ __launch_bounds__(256) void attn_mfma_kernel(const short* __restrict__ qb,
                                                        const short* __restrict__ kb,
                                                        const short* __restrict__ vt,
                                                        short* __restrict__ outb) {
    __shared__ __align__(16) short Qs[64][72];
    __shared__ __align__(16) short Ks[64][72];
    __shared__ __align__(16) short Vts[64][72];
    __shared__ __align__(16) short Ps[64][72];
    int q0 = blockIdx.x * 64;
    int bh = blockIdx.y;
    int h = bh & 7, b = bh >> 3;
    int tid = threadIdx.x;
    int lane = tid & 63, w = tid >> 6;
    int g = lane >> 4, r16 = lane & 15;
    const size_t hb = (size_t)bh * (2048 * 64);

#pragma unroll
    for (int p = 0; p < 4; p++) {
        int row = p * 16 + (tid >> 4);
        int c4 = (tid & 15) * 4;
        *(short4*)&Qs[row][c4] = *(const short4*)&qb[hb + (size_t)(q0 + row) * 64 + c4];
    }

    float m_[4], l_[4];
    f32x4 o_[4];
#pragma unroll
    for (int j = 0; j < 4; j++) { m_[j] = -1e30f; l_[j] = 0.f; }
#pragma unroll
    for (int c = 0; c < 4; c++) o_[c] = (f32x4)(0.f);

    for (int kt = 0; kt < 32; kt++) {
        int k0 = kt * 64;
        __syncthreads();
#pragma unroll
        for (int p = 0; p < 4; p++) {
            int row = p * 16 + (tid >> 4);
            int c4 = (tid & 15) * 4;
            *(short4*)&Ks[row][c4]  = *(const short4*)&kb[hb + (size_t)(k0 + row) * 64 + c4];
            *(short4*)&Vts[row][c4] = *(const short4*)&vt[hb + (size_t)row * 2048 + k0 + c4];
        }
        __syncthreads();

        bf16x8 aq0 = *(bf16x8*)&Qs[16 * w + r16][8 * g];
        bf16x8 aq1 = *(bf16x8*)&Qs[16 * w + r16][32 + 8 * g];
        f32x4 s[4];
#pragma unroll
        for (int c = 0; c < 4; c++) {
            bf16x8 bk0 = *(bf16x8*)&Ks[16 * c + r16][8 * g];
            bf16x8 bk1 = *(bf16x8*)&Ks[16 * c + r16][32 + 8 * g];
            f32x4 acc = (f32x4)(0.f);
            acc = __builtin_amdgcn_mfma_f32_16x16x32_bf16(aq0, bk0, acc, 0, 0, 0);
            acc = __builtin_amdgcn_mfma_f32_16x16x32_bf16(aq1, bk1, acc, 0, 0, 0);
            s[c] = acc;
        }

        float rm[4];
#pragma unroll
        for (int j = 0; j < 4; j++)
            rm[j] = fmaxf(fmaxf(s[0][j], s[1][j]), fmaxf(s[2][j], s[3][j])) * 0.125f;
#pragma unroll
        for (int off = 1; off < 16; off <<= 1)
#pragma unroll
            for (int j = 0; j < 4; j++) rm[j] = fmaxf(rm[j], __shfl_xor(rm[j], off));
        float alpha[4];
#pragma unroll
        for (int j = 0; j < 4; j++) {
            float mn = fmaxf(m_[j], rm[j]);
            alpha[j] = __expf(m_[j] - mn);
            m_[j] = mn;
        }
        float rs[4] = {0.f, 0.f, 0.f, 0.f};
        short pb[4][4];
#pragma unroll
        for (int c = 0; c < 4; c++)
#pragma unroll
            for (int j = 0; j < 4; j++) {
                float p = __expf(s[c][j] * 0.125f - m_[j]);
                rs[j] += p;
                pb[c][j] = f2bf(p);
            }
#pragma unroll
        for (int off = 1; off < 16; off <<= 1)
#pragma unroll
            for (int j = 0; j < 4; j++) rs[j] += __shfl_xor(rs[j], off);
#pragma unroll
        for (int j = 0; j < 4; j++) l_[j] = l_[j] * alpha[j] + rs[j];

#pragma unroll
        for (int c = 0; c < 4; c++)
#pragma unroll
            for (int j = 0; j < 4; j++)
                Ps[16 * w + 4 * g + j][16 * c + r16] = pb[c][j];
#pragma unroll
        for (int c = 0; c < 4; c++)
#pragma unroll
            for (int j = 0; j < 4; j++) o_[c][j] *= alpha[j];

        bf16x8 ap0 = *(bf16x8*)&Ps[16 * w + r16][8 * g];
        bf16x8 ap1 = *(bf16x8*)&Ps[16 * w + r16][32 + 8 * g];
#pragma unroll
        for (int c = 0; c < 4; c++) {
            bf16x8 bv0 = *(bf16x8*)&Vts[16 * c + r16][8 * g];
            bf16x8 bv1 = *(bf16x8*)&Vts[16 * c + r16][32 + 8 * g];
            o_[c] = __builtin_amdgcn_mfma_f32_16x16x32_bf16(ap0, bv0, o_[c], 0, 0, 0);
            o_[c] = __builtin_amdgcn_mfma_f32_16x16x32_bf16(ap1, bv1, o_[c], 0, 0, 0);
        }
    }

#pragma unroll
    for (int c = 0; c < 4; c++)
#pragma unroll
        for (int j = 0; j < 4; j++) {
            int qr = q0 + 16 * w + 4 * g + j;
            int d = 16 * c + r16;
            outb[((size_t)b * 2048 + qr) * 512 + h * 64 + d] = f2bf(o_[c][j] / l_[j]);
        }
}

// ---------------- silu(g) * u, bf16 in/out, 8-wide ----------------
__global__ __launch_bounds__(256) void silumul_b_kernel(const short* __restrict__ g,
                                                        const short* __restrict__ u,
                                                        short* __restrict__ o) {
    size_t i = ((size_t)blockIdx.x * 256 + threadIdx.x) * 8;
    bf16x8 gv = *(const bf16x8*)&g[i];
    bf16x8 uv = *(const bf16x8*)&u[i];
    bf16x8 ov;
#pragma unroll
    for (int j = 0; j < 8; j++) {
        float x = bf2f(gv[j]);
        float y = x / (1.f + __expf(-x)) * bf2f(uv[j]);
        ov[j] = f2bf(y);
    }
    *(bf16x8*)&o[i] = ov;
}

extern "C" void kernel_launch(void* const* d_in, const int* in_sizes, int n_in,
                              void* d_out, int out_size, void* d_ws, size_t ws_size,
                              hipStream_t stream) {
    const float* x      = (const float*)d_in[0];
    const float* ln1_w  = (const float*)d_in[1];
    const float* ln1_b  = (const float*)d_in[2];
    const float* ln2_w  = (const float*)d_in[3];
    const float* ln2_b  = (const float*)d_in[4];
    const float* wq     = (const float*)d_in[5];
    const float* wk     = (const float*)d_in[6];
    const float* wv     = (const float*)d_in[7];
    const float* wo     = (const float*)d_in[8];
    const float* w_gate = (const float*)d_in[9];
    const float* w_up   = (const float*)d_in[10];
    const float* w_down = (const float*)d_in[11];
    float* out = (float*)d_out;

    const int M = 4 * 2048;
    char* ws = (char*)d_ws;
    const size_t MB = 1 << 20;
    short* h1b   = (short*)(ws);               // 8 MB
    short* qb    = (short*)(ws + 8 * MB);      // 8 MB ; h2b reuses after attn
    short* kb    = (short*)(ws + 16 * MB);     // 8 MB
    short* vb    = (short*)(ws + 24 * MB);     // 8 MB
    short* vt    = (short*)(ws + 32 * MB);     // 8 MB
    short* aob   = (short*)(ws + 40 * MB);     // 8 MB  attn out bf16
    short* g_b   = (short*)(ws + 48 * MB);     // 16 MB
    short* u_b   = (short*)(ws + 64 * MB);     // 16 MB
    short* wqT   = (short*)(ws + 80 * MB);     // 0.5 MB each for q,k,v,o
    short* wkT   = (short*)(ws + 80 * MB + 512 * 1024);
    short* wvT   = (short*)(ws + 81 * MB);
    short* woT   = (short*)(ws + 81 * MB + 512 * 1024);
    short* wgT   = (short*)(ws + 82 * MB);     // 1 MB each
    short* wuT   = (short*)(ws + 83 * MB);
    short* wdT   = (short*)(ws + 84 * MB);
    short* h2b   = qb;

    WT7 wt;
    wt.a[0] = {wq,     wqT,  512,  512};
    wt.a[1] = {wk,     wkT,  512,  512};
    wt.a[2] = {wv,     wvT,  512,  512};
    wt.a[3] = {wo,     woT,  512,  512};
    wt.a[4] = {w_gate, wgT,  512, 1024};
    wt.a[5] = {w_up,   wuT,  512, 1024};
    wt.a[6] = {w_down, wdT, 1024,  512};

    dim3 g512(512 / 128, M / 128);   // 4 x 64
    dim3 g1024(1024 / 128, M / 128); // 8 x 64

    transp_w_kernel<<<dim3(32, 32, 7), 256, 0, stream>>>(wt);
    ln_kernel_b<<<M, 256, 0, stream>>>(x, ln1_w, ln1_b, h1b);
    gemm_mfma<2><<<g512, 256, 0, stream>>>(h1b, wqT, nullptr, qb, M, 512, 512);
    gemm_mfma<2><<<g512, 256, 0, stream>>>(h1b, wkT, nullptr, kb, M, 512, 512);
    gemm_mfma<2><<<g512, 256, 0, stream>>>(h1b, wvT, nullptr, vb, M, 512, 512);
    transp_v_kernel<<<dim3(32, 32), 256, 0, stream>>>(vb, vt);
    attn_mfma_kernel<<<dim3(32, 32), 256, 0, stream>>>(qb, kb, vt, aob);
    gemm_mfma<0><<<g512, 256, 0, stream>>>(aob, woT, x, out, M, 512, 512);
    ln_kernel_b<<<M, 256, 0, stream>>>(out, ln2_w, ln2_b, h2b);
    gemm_mfma<1><<<g1024, 256, 0, stream>>>(h2b, wgT, nullptr, g_b, M, 1024, 512);
    gemm_mfma<1><<<g1024, 256, 0, stream>>>(h2b, wuT, nullptr, u_b, M, 1024, 512);
    silumul_b_kernel<<<(M * 1024 / 8 + 255) / 256, 256, 0, stream>>>(g_b, u_b, g_b);
    gemm_mfma<0><<<g512, 256, 0, stream>>>(g_b, wdT, out, out, M, 512, 1024);
}

// Round 4
// 192.119 us; speedup vs baseline: 39.5386x; 1.5316x over previous
//
#include <hip/hip_runtime.h>
#include <hip/hip_bf16.h>
#include <math.h>

#define EPS 1e-5f

typedef __attribute__((ext_vector_type(8))) short bf16x8;
typedef __attribute__((ext_vector_type(4))) float f32x4;

__device__ __forceinline__ short f2bf(float x) {
    union { float f; unsigned u; } un; un.f = x;
    unsigned r = un.u + 0x7FFF + ((un.u >> 16) & 1);  // RNE
    return (short)(r >> 16);
}
__device__ __forceinline__ float bf2f(short s) {
    union { unsigned u; float f; } un;
    un.u = ((unsigned)(unsigned short)s) << 16;
    return un.f;
}
__device__ __forceinline__ unsigned pack_bf2(float a, float b) {
    unsigned r;
    asm("v_cvt_pk_bf16_f32 %0, %1, %2" : "=v"(r) : "v"(a), "v"(b));
    return r;
}
__device__ __forceinline__ float exp2_fast(float x) {
    float r;
    asm("v_exp_f32 %0, %1" : "=v"(r) : "v"(x));
    return r;
}
__device__ __forceinline__ void load_lds16(const short* g, short* l) {
    __builtin_amdgcn_global_load_lds(
        (const __attribute__((address_space(1))) unsigned int*)g,
        (__attribute__((address_space(3))) unsigned int*)l, 16, 0, 0);
}

// ---------------- LayerNorm: fp32 in -> bf16 out, one block per row ----------------
__global__ __launch_bounds__(256) void ln_kernel_b(const float* __restrict__ in,
                                                   const float* __restrict__ w,
                                                   const float* __restrict__ bb,
                                                   short* __restrict__ out) {
    int row = blockIdx.x;
    const float* x = in + (size_t)row * 512;
    short* o = out + (size_t)row * 512;
    int t = threadIdx.x;
    float v0 = x[t], v1 = x[t + 256];
    float s = v0 + v1;
    float s2 = v0 * v0 + v1 * v1;
    for (int off = 32; off > 0; off >>= 1) {
        s  += __shfl_down(s, off);
        s2 += __shfl_down(s2, off);
    }
    __shared__ float rs_[4], rs2_[4];
    __shared__ float mu_s, rstd_s;
    int wid = t >> 6;
    if ((t & 63) == 0) { rs_[wid] = s; rs2_[wid] = s2; }
    __syncthreads();
    if (t == 0) {
        float ts  = rs_[0] + rs_[1] + rs_[2] + rs_[3];
        float ts2 = rs2_[0] + rs2_[1] + rs2_[2] + rs2_[3];
        float mu  = ts * (1.f / 512.f);
        float var = ts2 * (1.f / 512.f) - mu * mu;
        mu_s = mu;
        rstd_s = rsqrtf(var + EPS);
    }
    __syncthreads();
    float mu = mu_s, rstd = rstd_s;
    o[t]       = f2bf((v0 - mu) * rstd * w[t]       + bb[t]);
    o[t + 256] = f2bf((v1 - mu) * rstd * w[t + 256] + bb[t + 256]);
}

// ---------------- weight transpose+cast: w[K][N] fp32 -> bt[N][K] bf16 (7 at once) ----------------
struct WT { const float* w; short* t; int K; int N; };
struct WT7 { WT a[7]; };
__global__ __launch_bounds__(256) void transp_w_kernel(WT7 p) {
    WT e = p.a[blockIdx.z];
    int k0 = blockIdx.x * 32, n0 = blockIdx.y * 32;
    if (k0 >= e.K || n0 >= e.N) return;
    __shared__ short t[32][33];
    int tx = threadIdx.x & 31, ty = threadIdx.x >> 5;  // 32 x 8
#pragma unroll
    for (int pp = 0; pp < 4; pp++)
        t[pp * 8 + ty][tx] = f2bf(e.w[(size_t)(k0 + pp * 8 + ty) * e.N + n0 + tx]);
    __syncthreads();
#pragma unroll
    for (int pp = 0; pp < 4; pp++)
        e.t[(size_t)(n0 + pp * 8 + ty) * e.K + k0 + tx] = t[tx][pp * 8 + ty];
}

// ---------------- bf16 MFMA GEMM: C[M,N] = A[M,K] @ Bt[N,K]^T ----------------
// 128x128 tile, BK=64, 4 waves 2x2, XOR-swizzled global_load_lds staging, XCD swizzle.
// EPI: 0 = fp32 C = res + acc (row-major)
//      2 = bf16 qkv packed [b,h,l,d]; q (n<512) pre-scaled by 0.125*log2e
//      3 = bf16 gate/up split: n<1024 -> C, n>=1024 -> C + 8388608
template <int EPI>
__global__ __launch_bounds__(256) void gemm_mfma(const short* __restrict__ A,
                                                 const short* __restrict__ Bt,
                                                 const float* __restrict__ res,
                                                 void* __restrict__ Cv,
                                                 int M, int N, int K) {
    __shared__ short As[128 * 64];
    __shared__ short Bs[128 * 64];
    const int tid = threadIdx.x;
    const int lane = tid & 63, w = tid >> 6;
    const int g = lane >> 4, r16 = lane & 15;
    const int wr = w >> 1, wc = w & 1;

    // XCD-aware bijective swizzle (grid size divisible by 8)
    const int nb = gridDim.x * gridDim.y;
    const int fid = blockIdx.y * gridDim.x + blockIdx.x;
    const int nid = (fid & 7) * (nb >> 3) + (fid >> 3);
    const int m0 = (nid / gridDim.x) * 128, n0 = (nid % gridDim.x) * 128;

    const int lr = lane >> 3;        // row within 8-row group
    const int ck = (lane & 7) ^ lr;  // inverse-swizzled source chunk
    const int row0 = w * 32;

    f32x4 acc[4][4] = {};

    for (int k0 = 0; k0 < K; k0 += 64) {
        __syncthreads();
#pragma unroll
        for (int p = 0; p < 4; p++) {
            int rb = row0 + p * 8;
            load_lds16(&A [(size_t)(m0 + rb + lr) * K + k0 + ck * 8], &As[rb * 64]);
            load_lds16(&Bt[(size_t)(n0 + rb + lr) * K + k0 + ck * 8], &Bs[rb * 64]);
        }
        __syncthreads();
#pragma unroll
        for (int ks = 0; ks < 2; ks++) {
            bf16x8 av[4], bv[4];
#pragma unroll
            for (int i = 0; i < 4; i++) {
                int row = wr * 64 + i * 16 + r16;
                av[i] = *(const bf16x8*)&As[row * 64 + ((ks * 4 + g) ^ (row & 7)) * 8];
            }
#pragma unroll
            for (int j = 0; j < 4; j++) {
                int row = wc * 64 + j * 16 + r16;
                bv[j] = *(const bf16x8*)&Bs[row * 64 + ((ks * 4 + g) ^ (row & 7)) * 8];
            }
#pragma unroll
            for (int i = 0; i < 4; i++)
#pragma unroll
                for (int j = 0; j < 4; j++)
                    acc[i][j] = __builtin_amdgcn_mfma_f32_16x16x32_bf16(av[i], bv[j], acc[i][j], 0, 0, 0);
        }
    }

#pragma unroll
    for (int i = 0; i < 4; i++)
#pragma unroll
        for (int j = 0; j < 4; j++)
#pragma unroll
            for (int jr = 0; jr < 4; jr++) {
                int m = m0 + wr * 64 + i * 16 + 4 * g + jr;
                int n = n0 + wc * 64 + j * 16 + r16;
                float v = acc[i][j][jr];
                if (EPI == 0) {
                    size_t idx = (size_t)m * N + n;
                    ((float*)Cv)[idx] = res[idx] + v;
                } else if (EPI == 2) {
                    if (n < 512) v *= 0.18033688011112042f;  // 0.125 * log2(e)
                    ((short*)Cv)[(size_t)(n >> 9) * 4194304 +
                                 (((size_t)(m >> 11) * 8 + ((n >> 6) & 7)) * 2048 + (m & 2047)) * 64 + (n & 63)] = f2bf(v);
                } else {
                    ((short*)Cv)[(size_t)(n >> 10) * 8388608 + (size_t)m * 1024 + (n & 1023)] = f2bf(v);
                }
            }
}

// ---------------- bf16 transpose V: [b,h,l,d] -> [b,h,d,l] ----------------
__global__ __launch_bounds__(256) void transp_v_kernel(const short* __restrict__ vb,
                                                       short* __restrict__ vt) {
    __shared__ short tile[64][65];
    int l0 = blockIdx.x * 64;
    int bh = blockIdx.y;
    const size_t base = (size_t)bh * 2048 * 64;
    int tid = threadIdx.x;
#pragma unroll
    for (int p = 0; p < 4; p++) {
        int r = p * 16 + (tid >> 4);
        int c4 = (tid & 15) * 4;
        *(short4*)&tile[r][c4] = *(const short4*)&vb[base + (size_t)(l0 + r) * 64 + c4];
    }
    __syncthreads();
#pragma unroll
    for (int p = 0; p < 4; p++) {
        int d = p * 16 + (tid >> 4);
        int c4 = (tid & 15) * 4;
        short4 o;
        o.x = tile[c4 + 0][d]; o.y = tile[c4 + 1][d];
        o.z = tile[c4 + 2][d]; o.w = tile[c4 + 3][d];
        *(short4*)&vt[base + (size_t)d * 2048 + l0 + c4] = o;
    }
}

// ---------------- MFMA flash attention: swapped QK^T, dbuf K/V, swizzled LDS ----------------
// grid 1024 blocks (XCD-swizzled -> bh-major), 4 waves; wave owns 16 q-rows.
// Q pre-scaled by 0.125*log2e; softmax in exp2 domain; defer-max THR=8.
__global__ __launch_bounds__(256) void attn_mfma_kernel(const short* __restrict__ qb,
                                                        const short* __restrict__ kb,
                                                        const short* __restrict__ vt,
                                                        short* __restrict__ outb) {
    __shared__ short QP[4096];      // Q tile, later per-wave P tiles (rows 16w..16w+15)
    __shared__ short Ks[2][4096];
    __shared__ short Vs[2][4096];

    const int fid = blockIdx.y * 32 + blockIdx.x;
    const int nid = (fid & 7) * 128 + (fid >> 3);  // bh-major within XCD
    const int bh = nid >> 5, qt = nid & 31;
    const int b = bh >> 3, h = bh & 7;
    const int q0 = qt * 64;
    const size_t hb = (size_t)bh * (2048 * 64);

    const int tid = threadIdx.x;
    const int lane = tid & 63, w = tid >> 6;
    const int g = lane >> 4, r16 = lane & 15;
    const int lr = lane >> 3, ck = (lane & 7) ^ lr;
    const int rx = r16 & 7;

    // stage Q (wave w -> rows 16w..16w+15)
    load_lds16(&qb[hb + (size_t)(q0 + 16 * w + lr) * 64 + ck * 8], &QP[(16 * w) * 64]);
    load_lds16(&qb[hb + (size_t)(q0 + 16 * w + 8 + lr) * 64 + ck * 8], &QP[(16 * w + 8) * 64]);

    auto stageKV = [&](int buf, int kt) {
        int k0 = kt * 64;
        int rb = w * 16;
        load_lds16(&kb[hb + (size_t)(k0 + rb + lr) * 64 + ck * 8],      &Ks[buf][rb * 64]);
        load_lds16(&kb[hb + (size_t)(k0 + rb + 8 + lr) * 64 + ck * 8],  &Ks[buf][(rb + 8) * 64]);
        load_lds16(&vt[hb + (size_t)(rb + lr) * 2048 + k0 + ck * 8],     &Vs[buf][rb * 64]);
        load_lds16(&vt[hb + (size_t)(rb + 8 + lr) * 2048 + k0 + ck * 8], &Vs[buf][(rb + 8) * 64]);
    };
    stageKV(0, 0);

    bf16x8 aq0, aq1;
    float m_ = -1e30f, l_ = 0.f;
    f32x4 ot[4] = {};
    int cur = 0;

    for (int t = 0; t < 32; t++) {
        __syncthreads();  // staged tile t visible (implicit vmcnt drain); prev compute done
        if (t == 0) {
            int row = 16 * w + r16;
            aq0 = *(const bf16x8*)&QP[row * 64 + ((0 + g) ^ rx) * 8];
            aq1 = *(const bf16x8*)&QP[row * 64 + ((4 + g) ^ rx) * 8];
        }
        if (t + 1 < 32) stageKV(cur ^ 1, t + 1);  // overlaps with compute below
        const short* Kc = &Ks[cur][0];
        const short* Vc = &Vs[cur][0];

        // ---- S^T = K @ Q^T : lane holds S[k=16c+4g+jr][q=r16], 16 k-values of one q-row ----
        f32x4 s[4];
#pragma unroll
        for (int c = 0; c < 4; c++) {
            int row = 16 * c + r16;
            bf16x8 ak0 = *(const bf16x8*)&Kc[row * 64 + ((0 + g) ^ rx) * 8];
            bf16x8 ak1 = *(const bf16x8*)&Kc[row * 64 + ((4 + g) ^ rx) * 8];
            f32x4 acc = {};
            acc = __builtin_amdgcn_mfma_f32_16x16x32_bf16(ak0, aq0, acc, 0, 0, 0);
            acc = __builtin_amdgcn_mfma_f32_16x16x32_bf16(ak1, aq1, acc, 0, 0, 0);
            s[c] = acc;
        }

        // ---- online softmax (exp2 domain, scalar state per lane) ----
        float pmax = s[0][0];
#pragma unroll
        for (int c = 0; c < 4; c++)
#pragma unroll
            for (int jr = 0; jr < 4; jr++)
                if (c || jr) pmax = fmaxf(pmax, s[c][jr]);
        pmax = fmaxf(pmax, __shfl_xor(pmax, 16));
        pmax = fmaxf(pmax, __shfl_xor(pmax, 32));
        if (!__all(pmax - m_ <= 8.f)) {  // defer-max: skip rescale when growth small
            float mn = fmaxf(m_, pmax);
            float al = exp2_fast(m_ - mn);
            l_ *= al;
#pragma unroll
            for (int c = 0; c < 4; c++) ot[c] *= al;
            m_ = mn;
        }
        float rs = 0.f;
#pragma unroll
        for (int c = 0; c < 4; c++) {
            float p0 = exp2_fast(s[c][0] - m_);
            float p1 = exp2_fast(s[c][1] - m_);
            float p2 = exp2_fast(s[c][2] - m_);
            float p3 = exp2_fast(s[c][3] - m_);
            rs += (p0 + p1) + (p2 + p3);
            unsigned lo = pack_bf2(p0, p1);
            unsigned hi = pack_bf2(p2, p3);
            int colbase = 16 * c + 4 * g;                       // k position
            int si = (16 * w + r16) * 64 + (((colbase >> 3) ^ rx) * 8) + (colbase & 7);
            *(unsigned*)&QP[si] = lo;
            *(unsigned*)&QP[si + 2] = hi;
        }
        rs += __shfl_xor(rs, 16);
        rs += __shfl_xor(rs, 32);
        l_ += rs;

        // ---- O^T += V^T @ P^T : lane accumulates O[q=r16][d=16c+4g+jr] ----
        int prow = 16 * w + r16;
        bf16x8 bp0 = *(const bf16x8*)&QP[prow * 64 + ((0 + g) ^ rx) * 8];
        bf16x8 bp1 = *(const bf16x8*)&QP[prow * 64 + ((4 + g) ^ rx) * 8];
#pragma unroll
        for (int c = 0; c < 4; c++) {
            int row = 16 * c + r16;
            bf16x8 av0 = *(const bf16x8*)&Vc[row * 64 + ((0 + g) ^ rx) * 8];
            bf16x8 av1 = *(const bf16x8*)&Vc[row * 64 + ((4 + g) ^ rx) * 8];
            ot[c] = __builtin_amdgcn_mfma_f32_16x16x32_bf16(av0, bp0, ot[c], 0, 0, 0);
            ot[c] = __builtin_amdgcn_mfma_f32_16x16x32_bf16(av1, bp1, ot[c], 0, 0, 0);
        }
        cur ^= 1;
    }

    // epilogue: lane's 16 O-values all belong to q-row r16 (+16w)
    float inv = 1.f / l_;
    int q = q0 + 16 * w + r16;
#pragma unroll
    for (int c = 0; c < 4; c++) {
        unsigned lo = pack_bf2(ot[c][0] * inv, ot[c][1] * inv);
        unsigned hi = pack_bf2(ot[c][2] * inv, ot[c][3] * inv);
        int d = 16 * c + 4 * g;
        size_t oi = ((size_t)b * 2048 + q) * 512 + h * 64 + d;
        *(unsigned*)&outb[oi] = lo;
        *(unsigned*)&outb[oi + 2] = hi;
    }
}

// ---------------- silu(g) * u, bf16 in/out, 8-wide ----------------
__global__ __launch_bounds__(256) void silumul_b_kernel(const short* __restrict__ g,
                                                        const short* __restrict__ u,
                                                        short* __restrict__ o) {
    size_t i = ((size_t)blockIdx.x * 256 + threadIdx.x) * 8;
    bf16x8 gv = *(const bf16x8*)&g[i];
    bf16x8 uv = *(const bf16x8*)&u[i];
    bf16x8 ov;
#pragma unroll
    for (int j = 0; j < 8; j++) {
        float x = bf2f(gv[j]);
        float y = x / (1.f + __expf(-x)) * bf2f(uv[j]);
        ov[j] = f2bf(y);
    }
    *(bf16x8*)&o[i] = ov;
}

extern "C" void kernel_launch(void* const* d_in, const int* in_sizes, int n_in,
                              void* d_out, int out_size, void* d_ws, size_t ws_size,
                              hipStream_t stream) {
    const float* x      = (const float*)d_in[0];
    const float* ln1_w  = (const float*)d_in[1];
    const float* ln1_b  = (const float*)d_in[2];
    const float* ln2_w  = (const float*)d_in[3];
    const float* ln2_b  = (const float*)d_in[4];
    const float* wq     = (const float*)d_in[5];
    const float* wk     = (const float*)d_in[6];
    const float* wv     = (const float*)d_in[7];
    const float* wo     = (const float*)d_in[8];
    const float* w_gate = (const float*)d_in[9];
    const float* w_up   = (const float*)d_in[10];
    const float* w_down = (const float*)d_in[11];
    float* out = (float*)d_out;

    const int M = 4 * 2048;
    char* ws = (char*)d_ws;
    const size_t MB = 1 << 20;
    short* h1b   = (short*)(ws);               // 8 MB
    short* qb    = (short*)(ws + 8 * MB);      // 8 MB (h2b reuse)
    short* kb    = (short*)(ws + 16 * MB);     // 8 MB (qb+4194304)
    short* vb    = (short*)(ws + 24 * MB);     // 8 MB (qb+2*4194304)
    short* vt    = (short*)(ws + 32 * MB);     // 8 MB
    short* aob   = (short*)(ws + 40 * MB);     // 8 MB
    short* g_b   = (short*)(ws + 48 * MB);     // 16 MB
    short* u_b   = (short*)(ws + 64 * MB);     // 16 MB (g_b+8388608)
    short* qkvT  = (short*)(ws + 80 * MB);     // 1.5 MB: wq|wk|wv rows
    short* woT   = (short*)(ws + 82 * MB);     // 0.5 MB
    short* wguT  = (short*)(ws + 83 * MB);     // 2 MB: gate|up rows
    short* wdT   = (short*)(ws + 85 * MB);     // 1 MB
    short* h2b   = qb;

    WT7 wt;
    wt.a[0] = {wq,     qkvT,               512,  512};
    wt.a[1] = {wk,     qkvT + 512 * 512,   512,  512};
    wt.a[2] = {wv,     qkvT + 1024 * 512,  512,  512};
    wt.a[3] = {wo,     woT,                512,  512};
    wt.a[4] = {w_gate, wguT,               512, 1024};
    wt.a[5] = {w_up,   wguT + 1024 * 512,  512, 1024};
    wt.a[6] = {w_down, wdT,               1024,  512};

    transp_w_kernel<<<dim3(32, 32, 7), 256, 0, stream>>>(wt);
    ln_kernel_b<<<M, 256, 0, stream>>>(x, ln1_w, ln1_b, h1b);
    gemm_mfma<2><<<dim3(12, 64), 256, 0, stream>>>(h1b, qkvT, nullptr, qb, M, 1536, 512);
    transp_v_kernel<<<dim3(32, 32), 256, 0, stream>>>(vb, vt);
    attn_mfma_kernel<<<dim3(32, 32), 256, 0, stream>>>(qb, kb, vt, aob);
    gemm_mfma<0><<<dim3(4, 64), 256, 0, stream>>>(aob, woT, x, out, M, 512, 512);
    ln_kernel_b<<<M, 256, 0, stream>>>(out, ln2_w, ln2_b, h2b);
    gemm_mfma<3><<<dim3(16, 64), 256, 0, stream>>>(h2b, wguT, nullptr, g_b, M, 2048, 512);
    silumul_b_kernel<<<(M * 1024 / 8 + 255) / 256, 256, 0, stream>>>(g_b, u_b, g_b);
    gemm_mfma<0><<<dim3(4, 64), 256, 0, stream>>>(g_b, wdT, out, out, M, 512, 1024);
}

// Round 5
// 183.138 us; speedup vs baseline: 41.4775x; 1.0490x over previous
//
#include <hip/hip_runtime.h>
#include <hip/hip_bf16.h>
#include <math.h>

#define EPS 1e-5f

typedef __attribute__((ext_vector_type(8))) short bf16x8;
typedef __attribute__((ext_vector_type(4))) float f32x4;

__device__ __forceinline__ short f2bf(float x) {
    union { float f; unsigned u; } un; un.f = x;
    unsigned r = un.u + 0x7FFF + ((un.u >> 16) & 1);  // RNE
    return (short)(r >> 16);
}
__device__ __forceinline__ float bf2f(short s) {
    union { unsigned u; float f; } un;
    un.u = ((unsigned)(unsigned short)s) << 16;
    return un.f;
}
__device__ __forceinline__ unsigned pack_bf2(float a, float b) {
    unsigned r;
    asm("v_cvt_pk_bf16_f32 %0, %1, %2" : "=v"(r) : "v"(a), "v"(b));
    return r;
}
__device__ __forceinline__ float exp2_fast(float x) {
    float r;
    asm("v_exp_f32 %0, %1" : "=v"(r) : "v"(x));
    return r;
}
__device__ __forceinline__ void load_lds16(const short* g, short* l) {
    __builtin_amdgcn_global_load_lds(
        (const __attribute__((address_space(1))) unsigned int*)g,
        (__attribute__((address_space(3))) unsigned int*)l, 16, 0, 0);
}

// ---------------- LayerNorm: fp32 -> bf16, one WAVE per row, 4 rows/block ----------------
__global__ __launch_bounds__(256) void ln_kernel_b(const float* __restrict__ in,
                                                   const float* __restrict__ w,
                                                   const float* __restrict__ bb,
                                                   short* __restrict__ out) {
    int wv = threadIdx.x >> 6, lane = threadIdx.x & 63;
    int row = blockIdx.x * 4 + wv;
    const float* x = in + (size_t)row * 512 + lane * 8;
    float4 v0 = *(const float4*)x;
    float4 v1 = *(const float4*)(x + 4);
    float s  = (v0.x + v0.y) + (v0.z + v0.w) + (v1.x + v1.y) + (v1.z + v1.w);
    float s2 = v0.x*v0.x + v0.y*v0.y + v0.z*v0.z + v0.w*v0.w
             + v1.x*v1.x + v1.y*v1.y + v1.z*v1.z + v1.w*v1.w;
#pragma unroll
    for (int off = 1; off < 64; off <<= 1) {
        s  += __shfl_xor(s, off);
        s2 += __shfl_xor(s2, off);
    }
    float mu = s * (1.f / 512.f);
    float rstd = rsqrtf(s2 * (1.f / 512.f) - mu * mu + EPS);
    const float4 wa = *(const float4*)&w[lane * 8];
    const float4 wb = *(const float4*)&w[lane * 8 + 4];
    const float4 ba = *(const float4*)&bb[lane * 8];
    const float4 bv = *(const float4*)&bb[lane * 8 + 4];
    uint4 o;
    o.x = pack_bf2((v0.x - mu) * rstd * wa.x + ba.x, (v0.y - mu) * rstd * wa.y + ba.y);
    o.y = pack_bf2((v0.z - mu) * rstd * wa.z + ba.z, (v0.w - mu) * rstd * wa.w + ba.w);
    o.z = pack_bf2((v1.x - mu) * rstd * wb.x + bv.x, (v1.y - mu) * rstd * wb.y + bv.y);
    o.w = pack_bf2((v1.z - mu) * rstd * wb.z + bv.z, (v1.w - mu) * rstd * wb.w + bv.w);
    *(uint4*)&out[(size_t)row * 512 + lane * 8] = o;
}

// ---------------- weight transpose+cast: w[K][N] fp32 -> bt[N][K] bf16 (7 at once) ----------------
struct WT { const float* w; short* t; int K; int N; };
struct WT7 { WT a[7]; };
__global__ __launch_bounds__(256) void transp_w_kernel(WT7 p) {
    WT e = p.a[blockIdx.z];
    int k0 = blockIdx.x * 32, n0 = blockIdx.y * 32;
    if (k0 >= e.K || n0 >= e.N) return;
    __shared__ short t[32][33];
    int tx = threadIdx.x & 31, ty = threadIdx.x >> 5;  // 32 x 8
#pragma unroll
    for (int pp = 0; pp < 4; pp++)
        t[pp * 8 + ty][tx] = f2bf(e.w[(size_t)(k0 + pp * 8 + ty) * e.N + n0 + tx]);
    __syncthreads();
#pragma unroll
    for (int pp = 0; pp < 4; pp++)
        e.t[(size_t)(n0 + pp * 8 + ty) * e.K + k0 + tx] = t[tx][pp * 8 + ty];
}

// ---------------- bf16 MFMA GEMM: C[M,N] = A[M,K] @ Bt[N,K]^T ----------------
// 128x128 tile, BK=64, 4 waves 2x2, XOR-swizzled global_load_lds staging, XCD swizzle.
// EPI: 0 = fp32 C = res + acc (row-major)
//      1 = bf16 C = acc (row-major)
//      2 = bf16 qkv packed [b,h,l,d]; q (n<512) pre-scaled by 0.125*log2e
//      4 = bf16 C = silu(resb) * acc (row-major)   [up-GEMM with gate fusion]
template <int EPI>
__global__ __launch_bounds__(256) void gemm_mfma(const short* __restrict__ A,
                                                 const short* __restrict__ Bt,
                                                 const float* __restrict__ res,
                                                 const short* __restrict__ resb,
                                                 void* __restrict__ Cv,
                                                 int M, int N, int K) {
    __shared__ short As[128 * 64];
    __shared__ short Bs[128 * 64];
    const int tid = threadIdx.x;
    const int lane = tid & 63, w = tid >> 6;
    const int g = lane >> 4, r16 = lane & 15;
    const int wr = w >> 1, wc = w & 1;

    // XCD-aware bijective swizzle (grid size divisible by 8)
    const int nb = gridDim.x * gridDim.y;
    const int fid = blockIdx.y * gridDim.x + blockIdx.x;
    const int nid = (fid & 7) * (nb >> 3) + (fid >> 3);
    const int m0 = (nid / gridDim.x) * 128, n0 = (nid % gridDim.x) * 128;

    const int lr = lane >> 3;        // row within 8-row group
    const int ck = (lane & 7) ^ lr;  // inverse-swizzled source chunk
    const int row0 = w * 32;

    f32x4 acc[4][4] = {};

    for (int k0 = 0; k0 < K; k0 += 64) {
        __syncthreads();
#pragma unroll
        for (int p = 0; p < 4; p++) {
            int rb = row0 + p * 8;
            load_lds16(&A [(size_t)(m0 + rb + lr) * K + k0 + ck * 8], &As[rb * 64]);
            load_lds16(&Bt[(size_t)(n0 + rb + lr) * K + k0 + ck * 8], &Bs[rb * 64]);
        }
        __syncthreads();
#pragma unroll
        for (int ks = 0; ks < 2; ks++) {
            bf16x8 av[4], bv[4];
#pragma unroll
            for (int i = 0; i < 4; i++) {
                int row = wr * 64 + i * 16 + r16;
                av[i] = *(const bf16x8*)&As[row * 64 + ((ks * 4 + g) ^ (row & 7)) * 8];
            }
#pragma unroll
            for (int j = 0; j < 4; j++) {
                int row = wc * 64 + j * 16 + r16;
                bv[j] = *(const bf16x8*)&Bs[row * 64 + ((ks * 4 + g) ^ (row & 7)) * 8];
            }
#pragma unroll
            for (int i = 0; i < 4; i++)
#pragma unroll
                for (int j = 0; j < 4; j++)
                    acc[i][j] = __builtin_amdgcn_mfma_f32_16x16x32_bf16(av[i], bv[j], acc[i][j], 0, 0, 0);
        }
    }

#pragma unroll
    for (int i = 0; i < 4; i++)
#pragma unroll
        for (int j = 0; j < 4; j++)
#pragma unroll
            for (int jr = 0; jr < 4; jr++) {
                int m = m0 + wr * 64 + i * 16 + 4 * g + jr;
                int n = n0 + wc * 64 + j * 16 + r16;
                float v = acc[i][j][jr];
                if (EPI == 0) {
                    size_t idx = (size_t)m * N + n;
                    ((float*)Cv)[idx] = res[idx] + v;
                } else if (EPI == 1) {
                    ((short*)Cv)[(size_t)m * N + n] = f2bf(v);
                } else if (EPI == 2) {
                    if (n < 512) v *= 0.18033688011112042f;  // 0.125 * log2(e)
                    ((short*)Cv)[(size_t)(n >> 9) * 4194304 +
                                 (((size_t)(m >> 11) * 8 + ((n >> 6) & 7)) * 2048 + (m & 2047)) * 64 + (n & 63)] = f2bf(v);
                } else {
                    float gt = bf2f(resb[(size_t)m * N + n]);
                    float y = gt / (1.f + __expf(-gt)) * v;
                    ((short*)Cv)[(size_t)m * N + n] = f2bf(y);
                }
            }
}

// ---------------- bf16 transpose V: [b,h,l,d] -> [b,h,d,l] ----------------
__global__ __launch_bounds__(256) void transp_v_kernel(const short* __restrict__ vb,
                                                       short* __restrict__ vt) {
    __shared__ short tile[64][65];
    int l0 = blockIdx.x * 64;
    int bh = blockIdx.y;
    const size_t base = (size_t)bh * 2048 * 64;
    int tid = threadIdx.x;
#pragma unroll
    for (int p = 0; p < 4; p++) {
        int r = p * 16 + (tid >> 4);
        int c4 = (tid & 15) * 4;
        *(short4*)&tile[r][c4] = *(const short4*)&vb[base + (size_t)(l0 + r) * 64 + c4];
    }
    __syncthreads();
#pragma unroll
    for (int p = 0; p < 4; p++) {
        int d = p * 16 + (tid >> 4);
        int c4 = (tid & 15) * 4;
        short4 o;
        o.x = tile[c4 + 0][d]; o.y = tile[c4 + 1][d];
        o.z = tile[c4 + 2][d]; o.w = tile[c4 + 3][d];
        *(short4*)&vt[base + (size_t)d * 2048 + l0 + c4] = o;
    }
}

// ---------------- MFMA flash attention: Q-tile 128, 32 q-rows/wave ----------------
// grid 512 blocks (XCD-swizzled, bh-major), 4 waves. Swapped QK^T; K/V frag reads
// amortized over 2 q-halves (32 MFMA per 16 b128 reads). dbuf K/V, swizzled LDS.
// Q pre-scaled by 0.125*log2e; softmax in exp2 domain; defer-max THR=8.
__global__ __launch_bounds__(256) void attn_mfma_kernel(const short* __restrict__ qb,
                                                        const short* __restrict__ kb,
                                                        const short* __restrict__ vt,
                                                        short* __restrict__ outb) {
    __shared__ short QP[128 * 64];   // Q tile, later per-wave P strips (rows 32w..32w+31)
    __shared__ short Ks[2][4096];
    __shared__ short Vs[2][4096];

    const int fid = blockIdx.y * gridDim.x + blockIdx.x;   // grid (16, 32)
    const int nid = (fid & 7) * 64 + (fid >> 3);           // bh-major within XCD
    const int bh = nid >> 4, qt = nid & 15;
    const int b = bh >> 3, h = bh & 7;
    const int q0 = qt * 128;
    const size_t hb = (size_t)bh * (2048 * 64);

    const int tid = threadIdx.x;
    const int lane = tid & 63, w = tid >> 6;
    const int g = lane >> 4, r16 = lane & 15;
    const int lr = lane >> 3, ck = (lane & 7) ^ lr;
    const int rx = r16 & 7;

    // stage Q: wave w -> rows 32w..32w+31
#pragma unroll
    for (int p = 0; p < 4; p++)
        load_lds16(&qb[hb + (size_t)(q0 + 32 * w + 8 * p + lr) * 64 + ck * 8],
                   &QP[(32 * w + 8 * p) * 64]);

    auto stageKV = [&](int buf, int kt) {
        int k0 = kt * 64;
        int rb = w * 16;
        load_lds16(&kb[hb + (size_t)(k0 + rb + lr) * 64 + ck * 8],      &Ks[buf][rb * 64]);
        load_lds16(&kb[hb + (size_t)(k0 + rb + 8 + lr) * 64 + ck * 8],  &Ks[buf][(rb + 8) * 64]);
        load_lds16(&vt[hb + (size_t)(rb + lr) * 2048 + k0 + ck * 8],     &Vs[buf][rb * 64]);
        load_lds16(&vt[hb + (size_t)(rb + 8 + lr) * 2048 + k0 + ck * 8], &Vs[buf][(rb + 8) * 64]);
    };
    stageKV(0, 0);

    bf16x8 aqA0, aqA1, aqB0, aqB1;
    float mA = -1e30f, lA = 0.f, mB = -1e30f, lB = 0.f;
    f32x4 oA[4] = {}, oB[4] = {};
    int cur = 0;

    for (int t = 0; t < 32; t++) {
        __syncthreads();  // staged tile t visible (vmcnt drained at barrier)
        if (t == 0) {
            int rowA = 32 * w + r16, rowB = rowA + 16;
            aqA0 = *(const bf16x8*)&QP[rowA * 64 + ((0 + g) ^ rx) * 8];
            aqA1 = *(const bf16x8*)&QP[rowA * 64 + ((4 + g) ^ rx) * 8];
            aqB0 = *(const bf16x8*)&QP[rowB * 64 + ((0 + g) ^ rx) * 8];
            aqB1 = *(const bf16x8*)&QP[rowB * 64 + ((4 + g) ^ rx) * 8];
        }
        if (t + 1 < 32) stageKV(cur ^ 1, t + 1);  // overlaps with compute below
        const short* Kc = &Ks[cur][0];
        const short* Vc = &Vs[cur][0];

        // ---- S^T = K @ Q^T for both q-halves; K frags read once ----
        f32x4 sA[4], sB[4];
#pragma unroll
        for (int c = 0; c < 4; c++) {
            int row = 16 * c + r16;
            bf16x8 ak0 = *(const bf16x8*)&Kc[row * 64 + ((0 + g) ^ rx) * 8];
            bf16x8 ak1 = *(const bf16x8*)&Kc[row * 64 + ((4 + g) ^ rx) * 8];
            f32x4 a1 = {}, a2 = {};
            a1 = __builtin_amdgcn_mfma_f32_16x16x32_bf16(ak0, aqA0, a1, 0, 0, 0);
            a1 = __builtin_amdgcn_mfma_f32_16x16x32_bf16(ak1, aqA1, a1, 0, 0, 0);
            a2 = __builtin_amdgcn_mfma_f32_16x16x32_bf16(ak0, aqB0, a2, 0, 0, 0);
            a2 = __builtin_amdgcn_mfma_f32_16x16x32_bf16(ak1, aqB1, a2, 0, 0, 0);
            sA[c] = a1; sB[c] = a2;
        }

        // ---- online softmax (exp2 domain, scalar state per lane per half) ----
        float pmA = sA[0][0], pmB = sB[0][0];
#pragma unroll
        for (int c = 0; c < 4; c++)
#pragma unroll
            for (int jr = 0; jr < 4; jr++) {
                if (c || jr) {
                    pmA = fmaxf(pmA, sA[c][jr]);
                    pmB = fmaxf(pmB, sB[c][jr]);
                }
            }
        pmA = fmaxf(pmA, __shfl_xor(pmA, 16));
        pmA = fmaxf(pmA, __shfl_xor(pmA, 32));
        pmB = fmaxf(pmB, __shfl_xor(pmB, 16));
        pmB = fmaxf(pmB, __shfl_xor(pmB, 32));
        if (!__all((pmA - mA <= 8.f) && (pmB - mB <= 8.f))) {
            float mnA = fmaxf(mA, pmA), mnB = fmaxf(mB, pmB);
            float alA = exp2_fast(mA - mnA), alB = exp2_fast(mB - mnB);
            lA *= alA; lB *= alB;
#pragma unroll
            for (int c = 0; c < 4; c++) { oA[c] *= alA; oB[c] *= alB; }
            mA = mnA; mB = mnB;
        }
        float rsA = 0.f, rsB = 0.f;
        int prA = 32 * w + r16, prB = prA + 16;
#pragma unroll
        for (int c = 0; c < 4; c++) {
            int colbase = 16 * c + 4 * g;
            int co = (((colbase >> 3) ^ rx) * 8) + (colbase & 7);
            {
                float p0 = exp2_fast(sA[c][0] - mA), p1 = exp2_fast(sA[c][1] - mA);
                float p2 = exp2_fast(sA[c][2] - mA), p3 = exp2_fast(sA[c][3] - mA);
                rsA += (p0 + p1) + (p2 + p3);
                unsigned long long pv = (unsigned long long)pack_bf2(p0, p1)
                                      | ((unsigned long long)pack_bf2(p2, p3) << 32);
                *(unsigned long long*)&QP[prA * 64 + co] = pv;
            }
            {
                float p0 = exp2_fast(sB[c][0] - mB), p1 = exp2_fast(sB[c][1] - mB);
                float p2 = exp2_fast(sB[c][2] - mB), p3 = exp2_fast(sB[c][3] - mB);
                rsB += (p0 + p1) + (p2 + p3);
                unsigned long long pv = (unsigned long long)pack_bf2(p0, p1)
                                      | ((unsigned long long)pack_bf2(p2, p3) << 32);
                *(unsigned long long*)&QP[prB * 64 + co] = pv;
            }
        }
        rsA += __shfl_xor(rsA, 16); rsA += __shfl_xor(rsA, 32); lA += rsA;
        rsB += __shfl_xor(rsB, 16); rsB += __shfl_xor(rsB, 32); lB += rsB;

        // ---- O^T += V^T @ P^T for both halves; V frags read once ----
        bf16x8 bpA0 = *(const bf16x8*)&QP[prA * 64 + ((0 + g) ^ rx) * 8];
        bf16x8 bpA1 = *(const bf16x8*)&QP[prA * 64 + ((4 + g) ^ rx) * 8];
        bf16x8 bpB0 = *(const bf16x8*)&QP[prB * 64 + ((0 + g) ^ rx) * 8];
        bf16x8 bpB1 = *(const bf16x8*)&QP[prB * 64 + ((4 + g) ^ rx) * 8];
#pragma unroll
        for (int c = 0; c < 4; c++) {
            int row = 16 * c + r16;
            bf16x8 av0 = *(const bf16x8*)&Vc[row * 64 + ((0 + g) ^ rx) * 8];
            bf16x8 av1 = *(const bf16x8*)&Vc[row * 64 + ((4 + g) ^ rx) * 8];
            oA[c] = __builtin_amdgcn_mfma_f32_16x16x32_bf16(av0, bpA0, oA[c], 0, 0, 0);
            oA[c] = __builtin_amdgcn_mfma_f32_16x16x32_bf16(av1, bpA1, oA[c], 0, 0, 0);
            oB[c] = __builtin_amdgcn_mfma_f32_16x16x32_bf16(av0, bpB0, oB[c], 0, 0, 0);
            oB[c] = __builtin_amdgcn_mfma_f32_16x16x32_bf16(av1, bpB1, oB[c], 0, 0, 0);
        }
        cur ^= 1;
    }

    // epilogue: lane's rows are q = q0+32w+r16 (half A) and +16 (half B)
    float ivA = 1.f / lA, ivB = 1.f / lB;
    int qa = q0 + 32 * w + r16;
#pragma unroll
    for (int c = 0; c < 4; c++) {
        int d = 16 * c + 4 * g;
        {
            unsigned long long pv = (unsigned long long)pack_bf2(oA[c][0] * ivA, oA[c][1] * ivA)
                                  | ((unsigned long long)pack_bf2(oA[c][2] * ivA, oA[c][3] * ivA) << 32);
            *(unsigned long long*)&outb[((size_t)b * 2048 + qa) * 512 + h * 64 + d] = pv;
        }
        {
            unsigned long long pv = (unsigned long long)pack_bf2(oB[c][0] * ivB, oB[c][1] * ivB)
                                  | ((unsigned long long)pack_bf2(oB[c][2] * ivB, oB[c][3] * ivB) << 32);
            *(unsigned long long*)&outb[((size_t)b * 2048 + qa + 16) * 512 + h * 64 + d] = pv;
        }
    }
}

extern "C" void kernel_launch(void* const* d_in, const int* in_sizes, int n_in,
                              void* d_out, int out_size, void* d_ws, size_t ws_size,
                              hipStream_t stream) {
    const float* x      = (const float*)d_in[0];
    const float* ln1_w  = (const float*)d_in[1];
    const float* ln1_b  = (const float*)d_in[2];
    const float* ln2_w  = (const float*)d_in[3];
    const float* ln2_b  = (const float*)d_in[4];
    const float* wq     = (const float*)d_in[5];
    const float* wk     = (const float*)d_in[6];
    const float* wv     = (const float*)d_in[7];
    const float* wo     = (const float*)d_in[8];
    const float* w_gate = (const float*)d_in[9];
    const float* w_up   = (const float*)d_in[10];
    const float* w_down = (const float*)d_in[11];
    float* out = (float*)d_out;

    const int M = 4 * 2048;
    char* ws = (char*)d_ws;
    const size_t MB = 1 << 20;
    short* h1b   = (short*)(ws);               // 8 MB
    short* qb    = (short*)(ws + 8 * MB);      // 8 MB (h2b reuse)
    short* kb    = (short*)(ws + 16 * MB);     // 8 MB (qb + 4194304)
    short* vb    = (short*)(ws + 24 * MB);     // 8 MB (qb + 2*4194304)
    short* vt    = (short*)(ws + 32 * MB);     // 8 MB
    short* aob   = (short*)(ws + 40 * MB);     // 8 MB
    short* g_b   = (short*)(ws + 48 * MB);     // 16 MB
    short* u_b   = (short*)(ws + 64 * MB);     // 16 MB
    short* qkvT  = (short*)(ws + 80 * MB);     // 1.5 MB: wq|wk|wv rows
    short* woT   = (short*)(ws + 82 * MB);     // 0.5 MB
    short* wguT  = (short*)(ws + 83 * MB);     // 2 MB: gate|up rows
    short* wdT   = (short*)(ws + 85 * MB);     // 1 MB
    short* h2b   = qb;

    WT7 wt;
    wt.a[0] = {wq,     qkvT,               512,  512};
    wt.a[1] = {wk,     qkvT + 512 * 512,   512,  512};
    wt.a[2] = {wv,     qkvT + 1024 * 512,  512,  512};
    wt.a[3] = {wo,     woT,                512,  512};
    wt.a[4] = {w_gate, wguT,               512, 1024};
    wt.a[5] = {w_up,   wguT + 1024 * 512,  512, 1024};
    wt.a[6] = {w_down, wdT,               1024,  512};

    transp_w_kernel<<<dim3(32, 32, 7), 256, 0, stream>>>(wt);
    ln_kernel_b<<<M / 4, 256, 0, stream>>>(x, ln1_w, ln1_b, h1b);
    gemm_mfma<2><<<dim3(12, 64), 256, 0, stream>>>(h1b, qkvT, nullptr, nullptr, qb, M, 1536, 512);
    transp_v_kernel<<<dim3(32, 32), 256, 0, stream>>>(vb, vt);
    attn_mfma_kernel<<<dim3(16, 32), 256, 0, stream>>>(qb, kb, vt, aob);
    gemm_mfma<0><<<dim3(4, 64), 256, 0, stream>>>(aob, woT, x, nullptr, out, M, 512, 512);
    ln_kernel_b<<<M / 4, 256, 0, stream>>>(out, ln2_w, ln2_b, h2b);
    gemm_mfma<1><<<dim3(8, 64), 256, 0, stream>>>(h2b, wguT, nullptr, nullptr, g_b, M, 1024, 512);
    gemm_mfma<4><<<dim3(8, 64), 256, 0, stream>>>(h2b, wguT + 1024 * 512, nullptr, g_b, u_b, M, 1024, 512);
    gemm_mfma<0><<<dim3(4, 64), 256, 0, stream>>>(u_b, wdT, out, nullptr, out, M, 512, 1024);
}